// Round 3
// baseline (1428.413 us; speedup 1.0000x reference)
//
#include <hip/hip_runtime.h>
#include <stdint.h>

#define TOKENS 2048
#define H_DIM 3584
#define I_DIM 18944

typedef int v4i __attribute__((ext_vector_type(4)));

__device__ __forceinline__ void async_copy16(const void* g, void* lds) {
    __builtin_amdgcn_global_load_lds(
        (const __attribute__((address_space(1))) void*)g,
        (__attribute__((address_space(3))) void*)lds,
        16, 0, 0);
}

// LDS swizzle: 16B chunk (row, kc) lives at row*64 + (kc ^ ((row>>1)&3))*16.
// Staging thread t owns physical chunk t (row=t>>2, slot=t&3), so it must
// fetch global k-chunk (t&3)^((t>>3)&3). Fragment reader at (row=fr, kc=fq)
// reads slot fq ^ ((fr>>1)&3). 8-way bank conflict -> 2-way (free, m136).

// ---------------------------------------------------------------------------
// Kernel 0: pack int32 weights (harness materializes int8 as int32) -> int8
// ---------------------------------------------------------------------------
__global__ __launch_bounds__(256)
void pack_kernel(const int* __restrict__ src, int8_t* __restrict__ dst, int n16) {
    int i = blockIdx.x * 256 + threadIdx.x;
    if (i >= n16) return;
    const v4i* s = (const v4i*)src + (size_t)i * 4;
    union { int8_t b[16]; v4i v; } o;
#pragma unroll
    for (int j = 0; j < 4; ++j) {
        v4i w = s[j];
        o.b[j * 4 + 0] = (int8_t)w.x;
        o.b[j * 4 + 1] = (int8_t)w.y;
        o.b[j * 4 + 2] = (int8_t)w.z;
        o.b[j * 4 + 3] = (int8_t)w.w;
    }
    ((v4i*)dst)[i] = o.v;
}

// ---------------------------------------------------------------------------
// Kernel 1: per-token dynamic symmetric int8 quant of x [T, H]
// ---------------------------------------------------------------------------
__global__ __launch_bounds__(256)
void quant_x_kernel(const float* __restrict__ x,
                    int8_t* __restrict__ qx,
                    float* __restrict__ sx) {
    const int row = blockIdx.x;
    const float* xr = x + (size_t)row * H_DIM;
    float m = 0.0f;
    for (int j = threadIdx.x; j < H_DIM; j += 256)
        m = fmaxf(m, fabsf(xr[j]));
    for (int off = 32; off > 0; off >>= 1)
        m = fmaxf(m, __shfl_down(m, off, 64));
    __shared__ float wmax[4];
    if ((threadIdx.x & 63) == 0) wmax[threadIdx.x >> 6] = m;
    __syncthreads();
    float mm = fmaxf(fmaxf(wmax[0], wmax[1]), fmaxf(wmax[2], wmax[3]));
    float s = fmaxf(mm / 127.0f, 1e-8f);
    if (threadIdx.x == 0) sx[row] = s;
    for (int j = threadIdx.x; j < H_DIM; j += 256) {
        float q = rintf(xr[j] / s);          // match jnp.round (half-even)
        q = fminf(fmaxf(q, -127.0f), 127.0f);
        qx[(size_t)row * H_DIM + j] = (int8_t)q;
    }
}

// ---------------------------------------------------------------------------
// Kernel 2: fused fc1 — gate & up int8 GEMM + SwiGLU + static requant
//   Block tile 128(M) x 64(N), BK=64. 4 waves, each wave 32x64 (x2 matrices).
// ---------------------------------------------------------------------------
__global__ __launch_bounds__(256)
void fc1_kernel(const int8_t* __restrict__ qx,
                const float* __restrict__ sx,
                const int8_t* __restrict__ gw,
                const int8_t* __restrict__ uw,
                const float* __restrict__ gws,
                const float* __restrict__ uws,
                const float* __restrict__ dis,
                int8_t* __restrict__ qh) {
    __shared__ __align__(16) int8_t ldsA[128 * 64];
    __shared__ __align__(16) int8_t ldsG[64 * 64];
    __shared__ __align__(16) int8_t ldsU[64 * 64];

    const int tid  = threadIdx.x;
    const int wave = tid >> 6;
    const int lane = tid & 63;
    const int n0 = blockIdx.x * 64;    // I dim
    const int m0 = blockIdx.y * 128;   // token dim

    // staging: thread t -> physical chunk t; fetch swizzled global k-chunk
    const int rowA  = tid >> 2;
    const int kOffB = (((tid & 3) ^ ((tid >> 3) & 3))) * 16;
    const int8_t* gA0 = qx + (size_t)(m0 + rowA) * H_DIM + kOffB;
    const int8_t* gA1 = qx + (size_t)(m0 + 64 + rowA) * H_DIM + kOffB;
    const int8_t* gG  = gw + (size_t)(n0 + rowA) * H_DIM + kOffB;
    const int8_t* gU  = uw + (size_t)(n0 + rowA) * H_DIM + kOffB;
    int8_t* lA0 = ldsA + tid * 16;
    int8_t* lA1 = ldsA + 4096 + tid * 16;
    int8_t* lG  = ldsG + tid * 16;
    int8_t* lU  = ldsU + tid * 16;

    const int fr = lane & 15;
    const int fq = lane >> 4;
    const int sw = fq ^ ((fr >> 1) & 3);       // swizzled k-chunk slot
    const int8_t* rA0 = ldsA + (wave * 32 + fr) * 64 + sw * 16;
    const int8_t* rA1 = rA0 + 16 * 64;
    const int8_t* rG  = ldsG + fr * 64 + sw * 16;
    const int8_t* rU  = ldsU + fr * 64 + sw * 16;

    v4i accG[2][4] = {};
    v4i accU[2][4] = {};

    for (int k0 = 0; k0 < H_DIM; k0 += 64) {
        __syncthreads();
        async_copy16(gA0 + k0, lA0);
        async_copy16(gA1 + k0, lA1);
        async_copy16(gG + k0, lG);
        async_copy16(gU + k0, lU);
        __syncthreads();
        v4i a0 = *(const v4i*)rA0;
        v4i a1 = *(const v4i*)rA1;
#pragma unroll
        for (int n = 0; n < 4; ++n) {
            v4i bg = *(const v4i*)(rG + n * 16 * 64);
            v4i bu = *(const v4i*)(rU + n * 16 * 64);
            accG[0][n] = __builtin_amdgcn_mfma_i32_16x16x64_i8(a0, bg, accG[0][n], 0, 0, 0);
            accG[1][n] = __builtin_amdgcn_mfma_i32_16x16x64_i8(a1, bg, accG[1][n], 0, 0, 0);
            accU[0][n] = __builtin_amdgcn_mfma_i32_16x16x64_i8(a0, bu, accU[0][n], 0, 0, 0);
            accU[1][n] = __builtin_amdgcn_mfma_i32_16x16x64_i8(a1, bu, accU[1][n], 0, 0, 0);
        }
    }

    const float gscale = *gws;
    const float uscale = *uws;
    const float dis_v  = *dis;

    // C/D layout: row = (lane>>4)*4 + r, col = lane&15
#pragma unroll
    for (int m = 0; m < 2; ++m) {
#pragma unroll
        for (int r = 0; r < 4; ++r) {
            const int row = m0 + wave * 32 + m * 16 + fq * 4 + r;
            const float s  = sx[row];
            const float gs = s * gscale;
            const float us = s * uscale;
            const size_t base = (size_t)row * I_DIM + n0;
#pragma unroll
            for (int n = 0; n < 4; ++n) {
                float g = (float)accG[m][n][r] * gs;
                float u = (float)accU[m][n][r] * us;
                float h = (g / (1.0f + expf(-g))) * u;   // silu(g) * u
                float q = rintf(h / dis_v);
                q = fminf(fmaxf(q, -127.0f), 127.0f);
                qh[base + n * 16 + fr] = (int8_t)q;
            }
        }
    }
}

// ---------------------------------------------------------------------------
// Kernel 3: fc2 — qh [T, I] int8 x down_w [H, I] int8 -> out [T, H] fp32
//   Block tile 128(M) x 64(N), BK=64 -> grid 56x16 = 896 blocks (was 448).
//   4 waves, each wave 32x64. acc = 32 regs/thread (was 64).
// ---------------------------------------------------------------------------
__global__ __launch_bounds__(256)
void fc2_kernel(const int8_t* __restrict__ qh,
                const int8_t* __restrict__ dw,
                const float* __restrict__ dws,
                const float* __restrict__ dis,
                float* __restrict__ out) {
    __shared__ __align__(16) int8_t ldsA[128 * 64];
    __shared__ __align__(16) int8_t ldsW[64 * 64];

    const int tid  = threadIdx.x;
    const int wave = tid >> 6;
    const int lane = tid & 63;
    const int n0 = blockIdx.x * 64;    // H dim
    const int m0 = blockIdx.y * 128;   // token dim

    const int rowA  = tid >> 2;
    const int kOffB = (((tid & 3) ^ ((tid >> 3) & 3))) * 16;
    const int8_t* gA0 = qh + (size_t)(m0 + rowA) * I_DIM + kOffB;
    const int8_t* gA1 = qh + (size_t)(m0 + 64 + rowA) * I_DIM + kOffB;
    const int8_t* gW  = dw + (size_t)(n0 + rowA) * I_DIM + kOffB;
    int8_t* lA0 = ldsA + tid * 16;
    int8_t* lA1 = ldsA + 4096 + tid * 16;
    int8_t* lW  = ldsW + tid * 16;

    const int fr = lane & 15;
    const int fq = lane >> 4;
    const int sw = fq ^ ((fr >> 1) & 3);
    const int8_t* rA0 = ldsA + (wave * 32 + fr) * 64 + sw * 16;
    const int8_t* rA1 = rA0 + 16 * 64;
    const int8_t* rW  = ldsW + fr * 64 + sw * 16;

    v4i acc[2][4] = {};

    for (int k0 = 0; k0 < I_DIM; k0 += 64) {
        __syncthreads();
        async_copy16(gA0 + k0, lA0);
        async_copy16(gA1 + k0, lA1);
        async_copy16(gW + k0, lW);
        __syncthreads();
        v4i a0 = *(const v4i*)rA0;
        v4i a1 = *(const v4i*)rA1;
#pragma unroll
        for (int n = 0; n < 4; ++n) {
            v4i b = *(const v4i*)(rW + n * 16 * 64);
            acc[0][n] = __builtin_amdgcn_mfma_i32_16x16x64_i8(a0, b, acc[0][n], 0, 0, 0);
            acc[1][n] = __builtin_amdgcn_mfma_i32_16x16x64_i8(a1, b, acc[1][n], 0, 0, 0);
        }
    }

    const float sc = (*dis) * (*dws);
#pragma unroll
    for (int m = 0; m < 2; ++m)
#pragma unroll
        for (int n = 0; n < 4; ++n)
#pragma unroll
            for (int r = 0; r < 4; ++r) {
                const int row = m0 + wave * 32 + m * 16 + fq * 4 + r;
                const int col = n0 + n * 16 + fr;
                out[(size_t)row * H_DIM + col] = (float)acc[m][n][r] * sc;
            }
}

// ---------------------------------------------------------------------------
extern "C" void kernel_launch(void* const* d_in, const int* in_sizes, int n_in,
                              void* d_out, int out_size, void* d_ws, size_t ws_size,
                              hipStream_t stream) {
    const float* x    = (const float*)d_in[0];
    const int*   gw32 = (const int*)d_in[1];   // integer inputs arrive as int32
    const int*   uw32 = (const int*)d_in[2];
    const int*   dw32 = (const int*)d_in[3];
    const float* gws  = (const float*)d_in[4];
    const float* uws  = (const float*)d_in[5];
    const float* dws  = (const float*)d_in[6];
    const float* dis  = (const float*)d_in[7];
    float* out = (float*)d_out;

    // workspace: qx [T*H] i8 | sx [T] f32 | qh [T*I] i8 | gw8 | uw8 | dw8
    const size_t W = (size_t)I_DIM * H_DIM;
    int8_t* qx  = (int8_t*)d_ws;
    float*  sx  = (float*)((char*)d_ws + (size_t)TOKENS * H_DIM);
    int8_t* qh  = (int8_t*)((char*)d_ws + (size_t)TOKENS * H_DIM + TOKENS * 4);
    int8_t* gw8 = (int8_t*)((char*)d_ws + (size_t)TOKENS * H_DIM + TOKENS * 4
                            + (size_t)TOKENS * I_DIM);
    int8_t* uw8 = gw8 + W;
    int8_t* dw8 = uw8 + W;

    const int n16 = (int)(W / 16);
    const int packBlocks = (n16 + 255) / 256;
    pack_kernel<<<packBlocks, 256, 0, stream>>>(gw32, gw8, n16);
    pack_kernel<<<packBlocks, 256, 0, stream>>>(uw32, uw8, n16);
    pack_kernel<<<packBlocks, 256, 0, stream>>>(dw32, dw8, n16);

    quant_x_kernel<<<TOKENS, 256, 0, stream>>>(x, qx, sx);

    dim3 g1(I_DIM / 64, TOKENS / 128);
    fc1_kernel<<<g1, 256, 0, stream>>>(qx, sx, gw8, uw8, gws, uws, dis, qh);

    dim3 g2(H_DIM / 64, TOKENS / 128);
    fc2_kernel<<<g2, 256, 0, stream>>>(qh, dw8, dws, dis, out);
}

// Round 4
// 1280.512 us; speedup vs baseline: 1.1155x; 1.1155x over previous
//
#include <hip/hip_runtime.h>
#include <stdint.h>

#define TOKENS 2048
#define H_DIM 3584
#define I_DIM 18944

typedef int v4i __attribute__((ext_vector_type(4)));

__device__ __forceinline__ void async_copy16(const void* g, void* lds) {
    __builtin_amdgcn_global_load_lds(
        (const __attribute__((address_space(1))) void*)g,
        (__attribute__((address_space(3))) void*)lds,
        16, 0, 0);
}

// BK=128 LDS swizzle: rows are 128 B = 8 slots of 16 B. Physical chunk
// (row, s) holds global k-chunk s ^ (row&7). Staging thread t (+j*256)
// owns rows (t>>3)+32j, slot t&7, so it fetches global k-chunk
// (t&7)^((t>>3)&7) — same offset for all j since 32j ≡ 0 (mod 8).
// Reader of (row=fr+16*m, logical chunk L=kh*4+fq) uses slot L^(fr&7):
// uniform 8 lanes per 16B slot -> ds_read_b128 bank floor, no conflicts.

// ---------------------------------------------------------------------------
// Kernel 0: pack int32-materialized int8 weights -> true int8
//   lane reads 16B contiguous (4 ints), writes 4B. Fully coalesced.
// ---------------------------------------------------------------------------
__global__ __launch_bounds__(256)
void pack_kernel(const int* __restrict__ src, int8_t* __restrict__ dst, int n4) {
    int i = blockIdx.x * 256 + threadIdx.x;
    if (i >= n4) return;
    v4i w = ((const v4i*)src)[i];
    int packed = (w.x & 0xff) | ((w.y & 0xff) << 8) |
                 ((w.z & 0xff) << 16) | (w.w << 24);
    ((int*)dst)[i] = packed;
}

// ---------------------------------------------------------------------------
// Kernel 1: per-token dynamic symmetric int8 quant of x [T, H]
// ---------------------------------------------------------------------------
__global__ __launch_bounds__(256)
void quant_x_kernel(const float* __restrict__ x,
                    int8_t* __restrict__ qx,
                    float* __restrict__ sx) {
    const int row = blockIdx.x;
    const float* xr = x + (size_t)row * H_DIM;
    float m = 0.0f;
    for (int j = threadIdx.x; j < H_DIM; j += 256)
        m = fmaxf(m, fabsf(xr[j]));
    for (int off = 32; off > 0; off >>= 1)
        m = fmaxf(m, __shfl_down(m, off, 64));
    __shared__ float wmax[4];
    if ((threadIdx.x & 63) == 0) wmax[threadIdx.x >> 6] = m;
    __syncthreads();
    float mm = fmaxf(fmaxf(wmax[0], wmax[1]), fmaxf(wmax[2], wmax[3]));
    float s = fmaxf(mm / 127.0f, 1e-8f);
    if (threadIdx.x == 0) sx[row] = s;
    for (int j = threadIdx.x; j < H_DIM; j += 256) {
        float q = rintf(xr[j] / s);          // match jnp.round (half-even)
        q = fminf(fmaxf(q, -127.0f), 127.0f);
        qx[(size_t)row * H_DIM + j] = (int8_t)q;
    }
}

// ---------------------------------------------------------------------------
// Kernel 2: fused fc1 — gate & up int8 GEMM + SwiGLU + static requant
//   Tile 128(M) x 64(N), BK=128. 4 waves, each 32x64 (x2 matrices).
//   32 MFMA per barrier pair. LDS = 32 KB.
// ---------------------------------------------------------------------------
__global__ __launch_bounds__(256)
void fc1_kernel(const int8_t* __restrict__ qx,
                const float* __restrict__ sx,
                const int8_t* __restrict__ gw,
                const int8_t* __restrict__ uw,
                const float* __restrict__ gws,
                const float* __restrict__ uws,
                const float* __restrict__ dis,
                int8_t* __restrict__ qh) {
    __shared__ __align__(16) int8_t ldsA[128 * 128];
    __shared__ __align__(16) int8_t ldsG[64 * 128];
    __shared__ __align__(16) int8_t ldsU[64 * 128];

    const int tid  = threadIdx.x;
    const int wave = tid >> 6;
    const int lane = tid & 63;
    const int n0 = blockIdx.x * 64;    // I dim
    const int m0 = blockIdx.y * 128;   // token dim

    // staging: thread t -> rows (t>>3)+32j, fixed swizzled k-offset
    const int rowS  = tid >> 3;                               // 0..31
    const int kOffS = (((tid & 7) ^ ((tid >> 3) & 7))) * 16;
    const int8_t* gA = qx + (size_t)(m0 + rowS) * H_DIM + kOffS;
    const int8_t* gG = gw + (size_t)(n0 + rowS) * H_DIM + kOffS;
    const int8_t* gU = uw + (size_t)(n0 + rowS) * H_DIM + kOffS;
    int8_t* lA = ldsA + tid * 16;
    int8_t* lG = ldsG + tid * 16;
    int8_t* lU = ldsU + tid * 16;

    const int fr = lane & 15;
    const int fq = lane >> 4;

    v4i accG[2][4] = {};
    v4i accU[2][4] = {};

    for (int k0 = 0; k0 < H_DIM; k0 += 128) {
        __syncthreads();
#pragma unroll
        for (int j = 0; j < 4; ++j)
            async_copy16(gA + k0 + (size_t)(32 * j) * H_DIM, lA + j * 4096);
#pragma unroll
        for (int j = 0; j < 2; ++j) {
            async_copy16(gG + k0 + (size_t)(32 * j) * H_DIM, lG + j * 4096);
            async_copy16(gU + k0 + (size_t)(32 * j) * H_DIM, lU + j * 4096);
        }
        __syncthreads();
#pragma unroll
        for (int kh = 0; kh < 2; ++kh) {
            const int sw = ((kh * 4 + fq) ^ (fr & 7)) * 16;   // phys slot byte
            v4i a0 = *(const v4i*)(ldsA + (wave * 32 + fr) * 128 + sw);
            v4i a1 = *(const v4i*)(ldsA + (wave * 32 + 16 + fr) * 128 + sw);
#pragma unroll
            for (int n = 0; n < 4; ++n) {
                v4i bg = *(const v4i*)(ldsG + (n * 16 + fr) * 128 + sw);
                v4i bu = *(const v4i*)(ldsU + (n * 16 + fr) * 128 + sw);
                accG[0][n] = __builtin_amdgcn_mfma_i32_16x16x64_i8(a0, bg, accG[0][n], 0, 0, 0);
                accG[1][n] = __builtin_amdgcn_mfma_i32_16x16x64_i8(a1, bg, accG[1][n], 0, 0, 0);
                accU[0][n] = __builtin_amdgcn_mfma_i32_16x16x64_i8(a0, bu, accU[0][n], 0, 0, 0);
                accU[1][n] = __builtin_amdgcn_mfma_i32_16x16x64_i8(a1, bu, accU[1][n], 0, 0, 0);
            }
        }
    }

    const float gscale = *gws;
    const float uscale = *uws;
    const float dis_v  = *dis;

    // C/D layout: row = (lane>>4)*4 + r, col = lane&15
#pragma unroll
    for (int m = 0; m < 2; ++m) {
#pragma unroll
        for (int r = 0; r < 4; ++r) {
            const int row = m0 + wave * 32 + m * 16 + fq * 4 + r;
            const float s  = sx[row];
            const float gs = s * gscale;
            const float us = s * uscale;
            const size_t base = (size_t)row * I_DIM + n0;
#pragma unroll
            for (int n = 0; n < 4; ++n) {
                float g = (float)accG[m][n][r] * gs;
                float u = (float)accU[m][n][r] * us;
                float h = (g / (1.0f + expf(-g))) * u;   // silu(g) * u
                float q = rintf(h / dis_v);
                q = fminf(fmaxf(q, -127.0f), 127.0f);
                qh[base + n * 16 + fr] = (int8_t)q;
            }
        }
    }
}

// ---------------------------------------------------------------------------
// Kernel 3: fc2 — qh [T, I] int8 x down_w [H, I] int8 -> out [T, H] fp32
//   Tile 128(M) x 64(N), BK=128 -> 896 blocks. 16 MFMA per barrier pair.
// ---------------------------------------------------------------------------
__global__ __launch_bounds__(256)
void fc2_kernel(const int8_t* __restrict__ qh,
                const int8_t* __restrict__ dw,
                const float* __restrict__ dws,
                const float* __restrict__ dis,
                float* __restrict__ out) {
    __shared__ __align__(16) int8_t ldsA[128 * 128];
    __shared__ __align__(16) int8_t ldsW[64 * 128];

    const int tid  = threadIdx.x;
    const int wave = tid >> 6;
    const int lane = tid & 63;
    const int n0 = blockIdx.x * 64;    // H dim
    const int m0 = blockIdx.y * 128;   // token dim

    const int rowS  = tid >> 3;
    const int kOffS = (((tid & 7) ^ ((tid >> 3) & 7))) * 16;
    const int8_t* gA = qh + (size_t)(m0 + rowS) * I_DIM + kOffS;
    const int8_t* gW = dw + (size_t)(n0 + rowS) * I_DIM + kOffS;
    int8_t* lA = ldsA + tid * 16;
    int8_t* lW = ldsW + tid * 16;

    const int fr = lane & 15;
    const int fq = lane >> 4;

    v4i acc[2][4] = {};

    for (int k0 = 0; k0 < I_DIM; k0 += 128) {
        __syncthreads();
#pragma unroll
        for (int j = 0; j < 4; ++j)
            async_copy16(gA + k0 + (size_t)(32 * j) * I_DIM, lA + j * 4096);
#pragma unroll
        for (int j = 0; j < 2; ++j)
            async_copy16(gW + k0 + (size_t)(32 * j) * I_DIM, lW + j * 4096);
        __syncthreads();
#pragma unroll
        for (int kh = 0; kh < 2; ++kh) {
            const int sw = ((kh * 4 + fq) ^ (fr & 7)) * 16;
            v4i a0 = *(const v4i*)(ldsA + (wave * 32 + fr) * 128 + sw);
            v4i a1 = *(const v4i*)(ldsA + (wave * 32 + 16 + fr) * 128 + sw);
#pragma unroll
            for (int n = 0; n < 4; ++n) {
                v4i b = *(const v4i*)(ldsW + (n * 16 + fr) * 128 + sw);
                acc[0][n] = __builtin_amdgcn_mfma_i32_16x16x64_i8(a0, b, acc[0][n], 0, 0, 0);
                acc[1][n] = __builtin_amdgcn_mfma_i32_16x16x64_i8(a1, b, acc[1][n], 0, 0, 0);
            }
        }
    }

    const float sc = (*dis) * (*dws);
#pragma unroll
    for (int m = 0; m < 2; ++m)
#pragma unroll
        for (int n = 0; n < 4; ++n)
#pragma unroll
            for (int r = 0; r < 4; ++r) {
                const int row = m0 + wave * 32 + m * 16 + fq * 4 + r;
                const int col = n0 + n * 16 + fr;
                out[(size_t)row * H_DIM + col] = (float)acc[m][n][r] * sc;
            }
}

// ---------------------------------------------------------------------------
extern "C" void kernel_launch(void* const* d_in, const int* in_sizes, int n_in,
                              void* d_out, int out_size, void* d_ws, size_t ws_size,
                              hipStream_t stream) {
    const float* x    = (const float*)d_in[0];
    const int*   gw32 = (const int*)d_in[1];   // integer inputs arrive as int32
    const int*   uw32 = (const int*)d_in[2];
    const int*   dw32 = (const int*)d_in[3];
    const float* gws  = (const float*)d_in[4];
    const float* uws  = (const float*)d_in[5];
    const float* dws  = (const float*)d_in[6];
    const float* dis  = (const float*)d_in[7];
    float* out = (float*)d_out;

    // workspace: qx [T*H] i8 | sx [T] f32 | qh [T*I] i8 | gw8 | uw8 | dw8
    const size_t W = (size_t)I_DIM * H_DIM;
    int8_t* qx  = (int8_t*)d_ws;
    float*  sx  = (float*)((char*)d_ws + (size_t)TOKENS * H_DIM);
    int8_t* qh  = (int8_t*)((char*)d_ws + (size_t)TOKENS * H_DIM + TOKENS * 4);
    int8_t* gw8 = (int8_t*)((char*)d_ws + (size_t)TOKENS * H_DIM + TOKENS * 4
                            + (size_t)TOKENS * I_DIM);
    int8_t* uw8 = gw8 + W;
    int8_t* dw8 = uw8 + W;

    const int n4 = (int)(W / 4);
    const int packBlocks = (n4 + 255) / 256;
    pack_kernel<<<packBlocks, 256, 0, stream>>>(gw32, gw8, n4);
    pack_kernel<<<packBlocks, 256, 0, stream>>>(uw32, uw8, n4);
    pack_kernel<<<packBlocks, 256, 0, stream>>>(dw32, dw8, n4);

    quant_x_kernel<<<TOKENS, 256, 0, stream>>>(x, qx, sx);

    dim3 g1(I_DIM / 64, TOKENS / 128);
    fc1_kernel<<<g1, 256, 0, stream>>>(qx, sx, gw8, uw8, gws, uws, dis, qh);

    dim3 g2(H_DIM / 64, TOKENS / 128);
    fc2_kernel<<<g2, 256, 0, stream>>>(qh, dw8, dws, dis, out);
}